// Round 9
// baseline (327.882 us; speedup 1.0000x reference)
//
#include <hip/hip_runtime.h>

#define BATCH 32
#define TIME  512
#define INF   512
#define HIDF  1024

#define MBT  128          // block tile: bt rows
#define NBH  128          // block tile: h cols
#define KCH  16           // k per chunk
#define NCH  (INF / KCH)  // 32 chunks
#define TILEF (MBT * KCH) // 2048 floats = 8 KB per buffer

// async global->LDS DMA, 16 B per lane, dst = wave-uniform base + lane*16
#define GLD16(g, l) __builtin_amdgcn_global_load_lds(                      \
    (const __attribute__((address_space(1))) void*)(g),                    \
    (__attribute__((address_space(3))) void*)(l), 16, 0, 0)

// ---------------------------------------------------------------------------
// Phase 1: hidden[bt][h] = (sum_k x[bt,k]*W[h,k]) + bias[h], bit-exact vs the
// XLA canonical order (verified R3): ONE fp32 accumulator per output, fused
// FMA, k strictly ascending, ONE fp32 rounding for +bias.
//
// R8 post-mortem: rows=ly*8+r kept all 8 addresses of a fragment read in one
// 16-bank half (row parity fixed by r) -> every b128 read 2-way conflicted
// (+2 cyc each, 1.7e7 conflict cycles). Fix: rows = ly + 8r, cols = lx + 8c.
// Row parity now alternates with ly/lx; XOR key (row>>1)&3 is lane-constant;
// the 8 addresses of each read cover 8 distinct bank-quads = all 32 banks,
// 1 address/quad -> conflict-free, and r/c become immediate offsets.
// ---------------------------------------------------------------------------
__global__ __launch_bounds__(256, 3)
void snn_gemm_seqfma(const float* __restrict__ x, const float* __restrict__ W,
                     const float* __restrict__ bias, float* __restrict__ hidden) {
    __shared__ __align__(16) float xs[2 * TILEF];   // 16 KB
    __shared__ __align__(16) float ws[2 * TILEF];   // 16 KB

    const int tid = threadIdx.x;
    const int l   = tid & 63;
    const int wv  = __builtin_amdgcn_readfirstlane(tid >> 6);  // wave 0..3
    const int lx  = l & 7;           // h lane: cols wh + lx + 8c
    const int ly  = (l >> 3) & 7;    // bt lane: rows wbt + ly + 8r
    const int bt0 = blockIdx.y * MBT;
    const int h0  = blockIdx.x * NBH;
    const int wbt = 64 * (wv >> 1);  // wave sub-tile origin: bt 0 or 64
    const int wh  = 64 * (wv & 1);   //                        h 0 or 64

    // ---- DMA staging: wave wv stages rows 32wv..32wv+31 of x and W.
    // LDS slot for (row, logical quad q): row*16 + (q ^ ((row>>1)&3))*4.
    // Lane i writes contiguous 16 B at 4i -> source quad = (i&3) ^ ((i>>3)&3).
    const int rl   = l >> 2;
    const int qs   = (l & 3) ^ ((rl >> 1) & 3);
    const int rowA = 32 * wv + rl;
    const int rowB = rowA + 16;                    // same key (16>>1 ≡ 0 mod 4)
    const float* xgA = x + (size_t)(bt0 + rowA) * INF + qs * 4;
    const float* xgB = x + (size_t)(bt0 + rowB) * INF + qs * 4;
    const float* wgA = W + (size_t)(h0 + rowA) * INF + qs * 4;
    const float* wgB = W + (size_t)(h0 + rowB) * INF + qs * 4;
    const int dOffA = (32 * wv) * KCH;             // wave-uniform float offset
    const int dOffB = dOffA + 16 * KCH;

    // ---- prologue: stage chunk 0 into buffer 0 ----
    GLD16(xgA, xs + dOffA);
    GLD16(xgB, xs + dOffB);
    GLD16(wgA, ws + dOffA);
    GLD16(wgB, ws + dOffB);

    float acc[8][8];
    #pragma unroll
    for (int r = 0; r < 8; ++r)
        #pragma unroll
        for (int c = 0; c < 8; ++c) acc[r][c] = 0.0f;

    const int keyx = (ly >> 1) & 3;   // lane-constant quad XOR keys
    const int keyw = (lx >> 1) & 3;

    __syncthreads();   // drains vmcnt -> chunk 0 resident

    for (int kc = 0; kc < NCH; ++kc) {
        const int p  = kc & 1;
        const int np = p ^ 1;

        // ---- issue next chunk's DMAs into the other buffer (async) ----
        if (kc + 1 < NCH) {
            const int so = (kc + 1) * KCH;
            float* xd = xs + np * TILEF;
            float* wd = ws + np * TILEF;
            GLD16(xgA + so, xd + dOffA);
            GLD16(xgB + so, xd + dOffB);
            GLD16(wgA + so, wd + dOffA);
            GLD16(wgB + so, wd + dOffB);
        }

        // ---- compute on current buffer: 4 groups of 4 k, g ascending ----
        const float* xrow = xs + p * TILEF + (wbt + ly) * KCH;
        const float* wrow = ws + p * TILEF + (wh  + lx) * KCH;
        #pragma unroll
        for (int g = 0; g < 4; ++g) {
            const float* xg_ = xrow + (g ^ keyx) * 4;
            const float* wg_ = wrow + (g ^ keyw) * 4;
            float4 xf[8], wf[8];
            #pragma unroll
            for (int r = 0; r < 8; ++r)
                xf[r] = *(const float4*)(xg_ + r * 8 * KCH);  // imm offsets
            #pragma unroll
            for (int c = 0; c < 8; ++c)
                wf[c] = *(const float4*)(wg_ + c * 8 * KCH);
            // k strictly ascending within the group for every (r,c) chain
            #pragma unroll
            for (int r = 0; r < 8; ++r)
                #pragma unroll
                for (int c = 0; c < 8; ++c)
                    acc[r][c] = __fmaf_rn(xf[r].x, wf[c].x, acc[r][c]);
            #pragma unroll
            for (int r = 0; r < 8; ++r)
                #pragma unroll
                for (int c = 0; c < 8; ++c)
                    acc[r][c] = __fmaf_rn(xf[r].y, wf[c].y, acc[r][c]);
            #pragma unroll
            for (int r = 0; r < 8; ++r)
                #pragma unroll
                for (int c = 0; c < 8; ++c)
                    acc[r][c] = __fmaf_rn(xf[r].z, wf[c].z, acc[r][c]);
            #pragma unroll
            for (int r = 0; r < 8; ++r)
                #pragma unroll
                for (int c = 0; c < 8; ++c)
                    acc[r][c] = __fmaf_rn(xf[r].w, wf[c].w, acc[r][c]);
        }
        __syncthreads();   // all waves done with buf p; buf np's DMAs drained
    }

    // ---- epilogue: one fp32 rounding for bias; rows/cols stride-8 per lane ----
    float bv[8];
    #pragma unroll
    for (int c = 0; c < 8; ++c) bv[c] = bias[h0 + wh + lx + 8 * c];
    #pragma unroll
    for (int r = 0; r < 8; ++r) {
        float* orow = hidden + (size_t)(bt0 + wbt + ly + 8 * r) * HIDF
                             + h0 + wh + lx;
        #pragma unroll
        for (int c = 0; c < 8; ++c)
            orow[8 * c] = __fadd_rn(acc[r][c], bv[c]);
    }
}

// ---------------------------------------------------------------------------
// Phase 2: in-place LIF scan over t per (b,h) column, fp32:
//   mem = fl32(0.5*mem + h_t); spk = mem > 1.0f; hard reset to 0.
// R8 bug: 128 blocks on 256 CUs left half the chip idle. Now 512 blocks x 64.
// ---------------------------------------------------------------------------
__global__ __launch_bounds__(64)
void snn_scan_np(float* __restrict__ io) {
    const int n = blockIdx.x * 64 + threadIdx.x;    // 0..32767
    const int b = n >> 10;
    const int h = n & 1023;
    float* p = io + (size_t)b * TIME * HIDF + h;

    float mem = 0.0f;
    for (int tb = 0; tb < TIME / 64; ++tb) {
        float hv[64];
        #pragma unroll
        for (int u = 0; u < 64; ++u) hv[u] = p[(size_t)(tb * 64 + u) * HIDF];
        float sp[64];
        #pragma unroll
        for (int u = 0; u < 64; ++u) {
            mem = __fadd_rn(__fmul_rn(0.5f, mem), hv[u]);
            bool s = mem > 1.0f;
            sp[u] = s ? 1.0f : 0.0f;
            if (s) mem = 0.0f;
        }
        #pragma unroll
        for (int u = 0; u < 64; ++u) p[(size_t)(tb * 64 + u) * HIDF] = sp[u];
    }
}

extern "C" void kernel_launch(void* const* d_in, const int* in_sizes, int n_in,
                              void* d_out, int out_size, void* d_ws, size_t ws_size,
                              hipStream_t stream) {
    const float* x    = (const float*)d_in[0];   // [32, 512, 512]
    const float* W    = (const float*)d_in[1];   // [1024, 512]
    const float* bias = (const float*)d_in[2];   // [1024]
    float* out = (float*)d_out;                  // [32, 512, 1024]

    dim3 g1(HIDF / NBH, (BATCH * TIME) / MBT);   // (8, 128) = 1024 blocks
    snn_gemm_seqfma<<<g1, 256, 0, stream>>>(x, W, bias, out);

    snn_scan_np<<<(BATCH * HIDF) / 64, 64, 0, stream>>>(out);
}